// Round 7
// baseline (214.663 us; speedup 1.0000x reference)
//
#include <hip/hip_runtime.h>

#define HW 2304
#define W48 48
#define RS_STRIDE 50       // Rs row stride in floats
#define RS_ROWS 52         // rows 0..51 hold R((r-2) mod 48)
#define RS_SIZE (RS_ROWS * RS_STRIDE)
#define NT 15              // timestep partials for the atomic spread

// ---------------------------------------------------------------------------
// prep: build rec_ext (float4: c0,c1,c2,walls) for all 16 timesteps,
//       build cur0 (frame 0 + walls), copy frame 0 (3ch) to d_out.
// ---------------------------------------------------------------------------
__global__ __launch_bounds__(256) void prep_kernel(
    const float* __restrict__ x, const float* __restrict__ rec,
    const float* __restrict__ walls,
    float4* __restrict__ rec4, float4* __restrict__ cur0,
    float* __restrict__ dout)
{
    int id = blockIdx.x * 256 + threadIdx.x;
    if (id < 16 * HW) {
        int t = id / HW, p = id % HW;
        rec4[id] = make_float4(rec[(t * 3 + 0) * HW + p],
                               rec[(t * 3 + 1) * HW + p],
                               rec[(t * 3 + 2) * HW + p],
                               walls[p]);
    }
    if (id < HW) {
        cur0[id] = make_float4(x[0 * HW + id], x[1 * HW + id], x[2 * HW + id],
                               walls[id]);
    }
    if (id < 3 * HW) {
        dout[id] = x[id];  // frame 0, channels 0..2
    }
}

// ---------------------------------------------------------------------------
// dist v7: block=(t,sy), 720 blocks x 384 threads (6 waves).
// r5 footprint (LDS = 2x Rs buffers, 20.8 KB; rec from L2 into 6 NAMED ring
// regs) + software pipelining: each iteration j issues the 10 ds_reads of
// R(j) FIRST, then computes F/R(j+1) into the other buffer (read latency
// hides under ~250 VALU cycles), then ring refill, then min(j), then one
// barrier. (384,2) avoids r5's spill. atomicMin goes to per-t partials
// (contention 720 -> 48 per address).
// Per-sx F/R/D expressions and summation order bit-identical to r4/r5/r6.
// ---------------------------------------------------------------------------
__global__ __launch_bounds__(384, 2) void dist_kernel(
    const float4* __restrict__ rec4, const float4* __restrict__ cur4,
    unsigned long long* __restrict__ best_part)
{
    __shared__ float Rs[2 * RS_SIZE];      // 20800 B

    const int tid = threadIdx.x;
    const int b   = blockIdx.x;
    const int sy  = b % W48;
    const int t   = b / W48;

    // AB ownership
    const int yA = tid >> 3;          // 0..47
    const int cA = tid & 7;           // 0..7
    const int x0 = 6 * cA;            // 0..42
    int ryA = yA + sy; if (ryA >= W48) ryA -= W48;

    // C ownership
    const int xC = tid % W48;
    const int y0 = 6 * (tid / W48);

    // bpermute byte-addresses: circular left/right neighbor within row-of-8
    const int lane  = tid & 63;
    const int addrL = ((lane & ~7) | ((cA + 7) & 7)) << 2;
    const int addrR = ((lane & ~7) | ((cA + 1) & 7)) << 2;

    unsigned int mb[6];
#pragma unroll
    for (int i = 0; i < 6; i++) {
        int ry = y0 + i + sy; if (ry >= W48) ry -= W48;
        mb[i] = (unsigned int)(t * HW + ry * W48);
    }

    // fixed cur window: cw_j = cur(yA, x0+j)   (x0+5 <= 47, no wrap)
    const float4* curRow = cur4 + yA * W48 + x0;
    const float4 cw0 = curRow[0];
    const float4 cw1 = curRow[1];
    const float4 cw2 = curRow[2];
    const float4 cw3 = curRow[3];
    const float4 cw4 = curRow[4];
    const float4 cw5 = curRow[5];

    // rec row base for this thread (L2-resident)
    const float4* recRow = rec4 + t * HW + ryA * W48;

    // 6-slot named ring: at iteration j, slot (j+k)%6 holds col (x0+j+k)%48
    float4 s0 = recRow[x0 + 0];
    float4 s1 = recRow[x0 + 1];
    float4 s2 = recRow[x0 + 2];
    float4 s3 = recRow[x0 + 3];
    float4 s4 = recRow[x0 + 4];
    float4 s5 = recRow[x0 + 5];

    int nc = x0 + 6; if (nc >= W48) nc -= W48;  // next ring col to fetch
    int rx = xC;                                 // candidate col (xC+j)%48

    unsigned long long bst[6];
#pragma unroll
    for (int i = 0; i < 6; i++) bst[i] = ~0ULL;

    unsigned long long* bt = best_part + (size_t)t * HW;

#define DIFF(D, C, Wv) do {                                                 \
        float d0 = (C).x - (Wv).x, d1 = (C).y - (Wv).y,                     \
              d2 = (C).z - (Wv).z, d3 = (C).w - (Wv).w;                     \
        D = d0 * d0 + d1 * d1 + d2 * d2 + d3 * d3;                          \
    } while (0)

// FRBLOCK: F from cw x ring slots, row box-sums, write to buffer BW.
#define FRBLOCK(BW, A0, A1, A2, A3, A4, A5) do {                            \
        float F0, F1, F2, F3, F4, F5;                                       \
        DIFF(F0, cw0, A0); DIFF(F1, cw1, A1); DIFF(F2, cw2, A2);            \
        DIFF(F3, cw3, A3); DIFF(F4, cw4, A4); DIFF(F5, cw5, A5);            \
        float Fm2 = __int_as_float(                                         \
            __builtin_amdgcn_ds_bpermute(addrL, __float_as_int(F4)));       \
        float Fm1 = __int_as_float(                                         \
            __builtin_amdgcn_ds_bpermute(addrL, __float_as_int(F5)));       \
        float F6  = __int_as_float(                                         \
            __builtin_amdgcn_ds_bpermute(addrR, __float_as_int(F0)));       \
        float F7  = __int_as_float(                                         \
            __builtin_amdgcn_ds_bpermute(addrR, __float_as_int(F1)));       \
        float R0 = Fm2 + Fm1 + F0 + F1 + F2;                                \
        float R1 = Fm1 + F0 + F1 + F2 + F3;                                 \
        float R2 = F0 + F1 + F2 + F3 + F4;                                  \
        float R3 = F1 + F2 + F3 + F4 + F5;                                  \
        float R4 = F2 + F3 + F4 + F5 + F6;                                  \
        float R5 = F3 + F4 + F5 + F6 + F7;                                  \
        float* RsB = &Rs[(BW) * RS_SIZE];                                   \
        {                                                                   \
            float* rw = &RsB[(yA + 2) * RS_STRIDE + x0];                    \
            *(float2*)&rw[0] = make_float2(R0, R1);                         \
            *(float2*)&rw[2] = make_float2(R2, R3);                         \
            *(float2*)&rw[4] = make_float2(R4, R5);                         \
        }                                                                   \
        if (yA < 2) {                                                       \
            float* rw = &RsB[(yA + 50) * RS_STRIDE + x0];                   \
            *(float2*)&rw[0] = make_float2(R0, R1);                         \
            *(float2*)&rw[2] = make_float2(R2, R3);                         \
            *(float2*)&rw[4] = make_float2(R4, R5);                         \
        }                                                                   \
        if (yA >= 46) {                                                     \
            float* rw = &RsB[(yA - 46) * RS_STRIDE + x0];                   \
            *(float2*)&rw[0] = make_float2(R0, R1);                         \
            *(float2*)&rw[2] = make_float2(R2, R3);                         \
            *(float2*)&rw[4] = make_float2(R4, R5);                         \
        }                                                                   \
    } while (0)

#define MINUPD do {                                                         \
        float d0 = rv0 + rv1 + rv2 + rv3 + rv4;                             \
        float d1 = rv1 + rv2 + rv3 + rv4 + rv5;                             \
        float d2 = rv2 + rv3 + rv4 + rv5 + rv6;                             \
        float d3 = rv3 + rv4 + rv5 + rv6 + rv7;                             \
        float d4 = rv4 + rv5 + rv6 + rv7 + rv8;                             \
        float d5 = rv5 + rv6 + rv7 + rv8 + rv9;                             \
        unsigned long long pk;                                              \
        pk = ((unsigned long long)__float_as_uint(d0) << 32) | (mb[0] + rx);\
        bst[0] = pk < bst[0] ? pk : bst[0];                                 \
        pk = ((unsigned long long)__float_as_uint(d1) << 32) | (mb[1] + rx);\
        bst[1] = pk < bst[1] ? pk : bst[1];                                 \
        pk = ((unsigned long long)__float_as_uint(d2) << 32) | (mb[2] + rx);\
        bst[2] = pk < bst[2] ? pk : bst[2];                                 \
        pk = ((unsigned long long)__float_as_uint(d3) << 32) | (mb[3] + rx);\
        bst[3] = pk < bst[3] ? pk : bst[3];                                 \
        pk = ((unsigned long long)__float_as_uint(d4) << 32) | (mb[4] + rx);\
        bst[4] = pk < bst[4] ? pk : bst[4];                                 \
        pk = ((unsigned long long)__float_as_uint(d5) << 32) | (mb[5] + rx);\
        bst[5] = pk < bst[5] ? pk : bst[5];                                 \
    } while (0)

// STEP_FULL(j): read R(j) from BR; compute+write R(j+1) to BW; refill A0's
// retiring register; min-update(j); barrier.
#define STEP_FULL(BR, BW, A0, A1, A2, A3, A4, A5) do {                      \
        const float* rp = &Rs[(BR) * RS_SIZE + y0 * RS_STRIDE + xC];        \
        float rv0 = rp[0 * RS_STRIDE];                                      \
        float rv1 = rp[1 * RS_STRIDE];                                      \
        float rv2 = rp[2 * RS_STRIDE];                                      \
        float rv3 = rp[3 * RS_STRIDE];                                      \
        float rv4 = rp[4 * RS_STRIDE];                                      \
        float rv5 = rp[5 * RS_STRIDE];                                      \
        float rv6 = rp[6 * RS_STRIDE];                                      \
        float rv7 = rp[7 * RS_STRIDE];                                      \
        float rv8 = rp[8 * RS_STRIDE];                                      \
        float rv9 = rp[9 * RS_STRIDE];                                      \
        FRBLOCK(BW, A0, A1, A2, A3, A4, A5);                                \
        A0 = recRow[nc];                                                    \
        nc++; if (nc >= W48) nc -= W48;                                     \
        MINUPD;                                                             \
        rx++; if (rx >= W48) rx -= W48;                                     \
        __syncthreads();                                                    \
    } while (0)

#define STEP_LAST(BR) do {                                                  \
        const float* rp = &Rs[(BR) * RS_SIZE + y0 * RS_STRIDE + xC];        \
        float rv0 = rp[0 * RS_STRIDE];                                      \
        float rv1 = rp[1 * RS_STRIDE];                                      \
        float rv2 = rp[2 * RS_STRIDE];                                      \
        float rv3 = rp[3 * RS_STRIDE];                                      \
        float rv4 = rp[4 * RS_STRIDE];                                      \
        float rv5 = rp[5 * RS_STRIDE];                                      \
        float rv6 = rp[6 * RS_STRIDE];                                      \
        float rv7 = rp[7 * RS_STRIDE];                                      \
        float rv8 = rp[8 * RS_STRIDE];                                      \
        float rv9 = rp[9 * RS_STRIDE];                                      \
        MINUPD;                                                             \
    } while (0)

    // prologue: R(0) -> buf0; refill slot0 with col x0+6; barrier
    FRBLOCK(0, s0, s1, s2, s3, s4, s5);
    s0 = recRow[nc];
    nc++; if (nc >= W48) nc -= W48;
    __syncthreads();

    // j = 0..41
    for (int so = 0; so < 7; so++) {
        STEP_FULL(0, 1, s1, s2, s3, s4, s5, s0);
        STEP_FULL(1, 0, s2, s3, s4, s5, s0, s1);
        STEP_FULL(0, 1, s3, s4, s5, s0, s1, s2);
        STEP_FULL(1, 0, s4, s5, s0, s1, s2, s3);
        STEP_FULL(0, 1, s5, s0, s1, s2, s3, s4);
        STEP_FULL(1, 0, s0, s1, s2, s3, s4, s5);
    }
    // j = 42..46
    STEP_FULL(0, 1, s1, s2, s3, s4, s5, s0);
    STEP_FULL(1, 0, s2, s3, s4, s5, s0, s1);
    STEP_FULL(0, 1, s3, s4, s5, s0, s1, s2);
    STEP_FULL(1, 0, s4, s5, s0, s1, s2, s3);
    STEP_FULL(0, 1, s5, s0, s1, s2, s3, s4);
    // j = 47 (reads buf1, no compute/barrier)
    STEP_LAST(1);

#undef STEP_LAST
#undef STEP_FULL
#undef MINUPD
#undef FRBLOCK
#undef DIFF

#pragma unroll
    for (int i = 0; i < 6; i++)
        atomicMin(&bt[(y0 + i) * W48 + xC], bst[i]);
}

// ---------------------------------------------------------------------------
// gather: reduce per-t partials; gather center pixel of (t+1) patch; write
// output frame + next carry + per-element sq-error.
// ---------------------------------------------------------------------------
__global__ __launch_bounds__(256) void gather_kernel(
    const unsigned long long* __restrict__ best_part,
    const float4* __restrict__ rec4, const float* __restrict__ x,
    const float* __restrict__ walls,
    float4* __restrict__ curnext, float* __restrict__ dout,
    float* __restrict__ err, int step)
{
    int p = blockIdx.x * 256 + threadIdx.x;
    if (p >= HW) return;
    unsigned long long bestv = ~0ULL;
#pragma unroll
    for (int j = 0; j < NT; j++) {
        unsigned long long v = best_part[(size_t)j * HW + p];
        bestv = v < bestv ? v : bestv;
    }
    unsigned int m = (unsigned int)bestv;
    int t = m / HW, q = m % HW;
    float4 v = rec4[(t + 1) * HW + q];
    curnext[p] = v;
    dout[(step + 1) * 3 * HW + 0 * HW + p] = v.x;
    dout[(step + 1) * 3 * HW + 1 * HW + p] = v.y;
    dout[(step + 1) * 3 * HW + 2 * HW + p] = v.z;
    float t0 = x[((step + 1) * 3 + 0) * HW + p];
    float t1 = x[((step + 1) * 3 + 1) * HW + p];
    float t2 = x[((step + 1) * 3 + 2) * HW + p];
    float t3 = walls[p];
    float e = (v.x - t0) * (v.x - t0) + (v.y - t1) * (v.y - t1) +
              (v.z - t2) * (v.z - t2) + (v.w - t3) * (v.w - t3);
    err[step * HW + p] = e;
}

// ---------------------------------------------------------------------------
// loss: deterministic reduction; loss = total / 18432.
// ---------------------------------------------------------------------------
__global__ __launch_bounds__(256) void loss_kernel(
    const float* __restrict__ err, float* __restrict__ dout)
{
    __shared__ float ssum[256];
    float s = 0.f;
    for (int i = threadIdx.x; i < 2 * HW; i += 256) s += err[i];
    ssum[threadIdx.x] = s;
    __syncthreads();
    for (int w = 128; w > 0; w >>= 1) {
        if (threadIdx.x < w) ssum[threadIdx.x] += ssum[threadIdx.x + w];
        __syncthreads();
    }
    if (threadIdx.x == 0) dout[9 * HW] = ssum[0] / 18432.0f;
}

extern "C" void kernel_launch(void* const* d_in, const int* in_sizes, int n_in,
                              void* d_out, int out_size, void* d_ws,
                              size_t ws_size, hipStream_t stream)
{
    const float* x     = (const float*)d_in[0];
    const float* rec   = (const float*)d_in[1];
    const float* walls = (const float*)d_in[2];
    float* dout = (float*)d_out;

    char* ws = (char*)d_ws;
    float4* rec4 = (float4*)ws;                               // 589824 B
    float4* curb = (float4*)(ws + 589824);                    // 110592 B
    float*  err  = (float*)(ws + 589824 + 110592);            //  18432 B
    unsigned long long* best_part =
        (unsigned long long*)(ws + 589824 + 110592 + 18432);  // 276480 B

    prep_kernel<<<144, 256, 0, stream>>>(x, rec, walls, rec4, curb, dout);
    for (int step = 0; step < 2; step++) {
        hipMemsetAsync(best_part, 0xFF, (size_t)NT * HW * 8, stream);
        dist_kernel<<<NT * W48, 384, 0, stream>>>(rec4, curb + step * HW,
                                                  best_part);
        gather_kernel<<<9, 256, 0, stream>>>(best_part, rec4, x, walls,
                                             curb + (step + 1) * HW, dout, err,
                                             step);
    }
    loss_kernel<<<1, 256, 0, stream>>>(err, dout);
}